// Round 3
// baseline (284.527 us; speedup 1.0000x reference)
//
#include <hip/hip_runtime.h>
#include <cstdint>

#define ZFULL 136
#define NCTX 16
#define KCLS 75

typedef __bf16 bf16x8 __attribute__((ext_vector_type(8)));
typedef float f32x4 __attribute__((ext_vector_type(4)));

__device__ __forceinline__ ushort bf16_rne(float v) {
  uint32_t u = __float_as_uint(v);
  return (ushort)((u + 0x7fffu + ((u >> 16) & 1u)) >> 16);
}

// ---- pack A: [CH/16 m_tiles][5 k_tiles][2 h][64 lane][8 j] ushorts (bf16) ----
__global__ __launch_bounds__(256) void pack_A(const float* __restrict__ z,
                                              const int* __restrict__ labels,
                                              ushort* __restrict__ Apk,
                                              int b0, int CH) {
  int idx = blockIdx.x * 256 + threadIdx.x;  // (mt,kt,h,lane)
  int lane = idx & 63;
  int h = (idx >> 6) & 1;
  int kt = (idx >> 7) % 5;
  int mt = idx / 640;
  if (mt >= CH / 16) return;
  int m = b0 + mt * 16 + (lane & 15);
  int kbase = kt * 32 + (lane >> 4) * 8;
  ushort o[8];
#pragma unroll
  for (int j = 0; j < 8; ++j) {
    int k = kbase + j;
    float v = 0.0f;
    if (k < ZFULL) v = z[(size_t)m * ZFULL + k];
    else if (k < ZFULL + NCTX) v = (float)labels[(size_t)m * NCTX + (k - ZFULL)];
    ushort hi = bf16_rne(v);
    if (h == 0) o[j] = hi;
    else {
      float fhi = __uint_as_float((uint32_t)hi << 16);
      o[j] = bf16_rne(v - fhi);
    }
  }
  uint4 w;
  w.x = (uint32_t)o[0] | ((uint32_t)o[1] << 16);
  w.y = (uint32_t)o[2] | ((uint32_t)o[3] << 16);
  w.z = (uint32_t)o[4] | ((uint32_t)o[5] << 16);
  w.w = (uint32_t)o[6] | ((uint32_t)o[7] << 16);
  *(uint4*)(Apk + (size_t)idx * 8) = w;
}

// ---- pack B: [256 n_tiles][5 k_tiles][2 h][64 lane][8 j] ushorts (bf16) ----
__global__ __launch_bounds__(256) void pack_B(const float* __restrict__ Kp,
                                              const float* __restrict__ Lm,
                                              ushort* __restrict__ Bpk) {
  int idx = blockIdx.x * 256 + threadIdx.x;
  int lane = idx & 63;
  int h = (idx >> 6) & 1;
  int kt = (idx >> 7) % 5;
  int nt = idx / 640;
  if (nt >= 256) return;
  int n = nt * 16 + (lane & 15);
  int kbase = kt * 32 + (lane >> 4) * 8;
  ushort o[8];
#pragma unroll
  for (int j = 0; j < 8; ++j) {
    int k = kbase + j;
    float v = 0.0f;
    if (k < ZFULL) v = Kp[(size_t)n * ZFULL + k];
    else if (k < ZFULL + NCTX) v = Lm[(size_t)n * NCTX + (k - ZFULL)];
    ushort hi = bf16_rne(v);
    if (h == 0) o[j] = hi;
    else {
      float fhi = __uint_as_float((uint32_t)hi << 16);
      o[j] = bf16_rne(v - fhi);
    }
  }
  uint4 w;
  w.x = (uint32_t)o[0] | ((uint32_t)o[1] << 16);
  w.y = (uint32_t)o[2] | ((uint32_t)o[3] << 16);
  w.z = (uint32_t)o[4] | ((uint32_t)o[5] << 16);
  w.w = (uint32_t)o[6] | ((uint32_t)o[7] << 16);
  *(uint4*)(Bpk + (size_t)idx * 8) = w;
}

// ---- split-bf16 MFMA GEMM, 128x128 block tile, no LDS (L2-resident packed operands) ----
__global__ __launch_bounds__(256) void gemm_mfma(const ushort* __restrict__ Apk,
                                                 const ushort* __restrict__ Bpk,
                                                 const float* __restrict__ base_log,
                                                 float* __restrict__ rates) {
  const int tid = threadIdx.x;
  const int lane = tid & 63;
  const int w = tid >> 6;
  const int wm = w & 1, wn = w >> 1;
  const int m_tile0 = blockIdx.x * 8 + wm * 4;
  const int n_tile0 = blockIdx.y * 8 + wn * 4;

  f32x4 acc[4][4] = {};

#pragma unroll
  for (int kt = 0; kt < 5; ++kt) {
    bf16x8 ah[4], al[4], bh[4], bl[4];
#pragma unroll
    for (int mt = 0; mt < 4; ++mt) {
      size_t off = (((size_t)(m_tile0 + mt) * 5 + kt) * 128 + lane) * 8;
      ah[mt] = *(const bf16x8*)(Apk + off);
      al[mt] = *(const bf16x8*)(Apk + off + 512);
    }
#pragma unroll
    for (int nt = 0; nt < 4; ++nt) {
      size_t off = (((size_t)(n_tile0 + nt) * 5 + kt) * 128 + lane) * 8;
      bh[nt] = *(const bf16x8*)(Bpk + off);
      bl[nt] = *(const bf16x8*)(Bpk + off + 512);
    }
#pragma unroll
    for (int mt = 0; mt < 4; ++mt)
#pragma unroll
      for (int nt = 0; nt < 4; ++nt) {
        acc[mt][nt] = __builtin_amdgcn_mfma_f32_16x16x32_bf16(ah[mt], bh[nt], acc[mt][nt], 0, 0, 0);
        acc[mt][nt] = __builtin_amdgcn_mfma_f32_16x16x32_bf16(ah[mt], bl[nt], acc[mt][nt], 0, 0, 0);
        acc[mt][nt] = __builtin_amdgcn_mfma_f32_16x16x32_bf16(al[mt], bh[nt], acc[mt][nt], 0, 0, 0);
      }
  }

  const int col_l = lane & 15;
  const int row_l = (lane >> 4) * 4;
#pragma unroll
  for (int mt = 0; mt < 4; ++mt) {
#pragma unroll
    for (int nt = 0; nt < 4; ++nt) {
      int n = (n_tile0 + nt) * 16 + col_l;
      int i = n >> 6, j = n & 63;
      float bse = base_log[n];
#pragma unroll
      for (int r = 0; r < 4; ++r) {
        int m = (m_tile0 + mt) * 16 + row_l + r;
        float v = acc[mt][nt][r] + bse;
        v = fminf(fmaxf(v, -15.0f), 3.0f);
        float e = (i == j) ? 0.0f : expf(v);
        rates[(size_t)m * 4096 + n] = e;
      }
    }
  }
}

// ===== statically-unrolled Gaussian elimination (forces a[] into VGPRs) =====
template <int K>
struct GE {
  static __device__ __forceinline__ void run(float (&a)[64]) {
    float piv = __shfl(a[K], K);
    float rp = __builtin_amdgcn_rcpf(piv);
    a[K] *= rp;  // pivot row now has exact 1.0 at column K on lane K
#pragma unroll
    for (int i = K + 1; i < 64; ++i) {
      float c = __shfl(a[i], K);
      a[i] = fmaf(-c, a[K], a[i]);
    }
    GE<K + 1>::run(a);
  }
};
template <>
struct GE<63> {
  static __device__ __forceinline__ void run(float (&)[64]) {}
};

// ===== statically-unrolled back-substitution (lane j accumulates x[j]) =====
template <int K>
struct BS {
  static __device__ __forceinline__ void run(float (&a)[64], float& x, int lane) {
    float t = a[K] * x;  // nonzero only at solved lanes j>K (subdiag entries are exact 0)
    t += __shfl_xor(t, 32); t += __shfl_xor(t, 16); t += __shfl_xor(t, 8);
    t += __shfl_xor(t, 4);  t += __shfl_xor(t, 2);  t += __shfl_xor(t, 1);
    if (lane == K) x = -t;  // b[K]=0, unit diagonal
    BS<K - 1>::run(a, x, lane);
  }
};
template <>
struct BS<-1> {
  static __device__ __forceinline__ void run(float (&)[64], float&, int) {}
};

// ---- solve + attention + logits: one wave per batch, lane = column ----
__global__ __launch_bounds__(256) void solve_kernel(const float* __restrict__ rates,
                                                    const int* __restrict__ labels,
                                                    const float* __restrict__ Bm,
                                                    float* __restrict__ out,
                                                    int b0) {
  __shared__ float Blds[64][16];
  __shared__ float xbuf[4][64];
  __shared__ float att_lds[4][16];
  __shared__ float acc[4][80];

  const int tid = threadIdx.x;
  for (int idx = tid; idx < 1024; idx += 256)
    Blds[idx >> 4][idx & 15] = Bm[idx];

  const int wave = tid >> 6;
  const int lane = tid & 63;
  const int batch = b0 + blockIdx.x * 4 + wave;
  const float* R = rates + (size_t)(blockIdx.x * 4 + wave) * 4096;

  // lane holds column `lane`: a[i] = K[i][lane]
  float a[64];
#pragma unroll
  for (int i = 0; i < 64; ++i) a[i] = R[i * 64 + lane];

  float cs = 0.0f;  // col_sum (diag entry is 0 from GEMM)
#pragma unroll
  for (int i = 0; i < 64; ++i) cs += a[i];
#pragma unroll
  for (int i = 0; i < 63; ++i) a[i] = (lane == i) ? -cs : a[i];
  a[63] = 1.0f;  // normalization row

  // GE without pivoting (leading block column-diag-dominant); b=e63 untouched.
  GE<0>::run(a);

  // back-substitution
  float x = 0.0f;
  {
    float d = __shfl(a[63], 63);
    float x63 = 1.0f / d;
    if (lane == 63) x = x63;
  }
  BS<62>::run(a, x, lane);

  // clip >= 0 and normalize
  x = fmaxf(x, 0.0f);
  float s = x;
  s += __shfl_xor(s, 32); s += __shfl_xor(s, 16); s += __shfl_xor(s, 8);
  s += __shfl_xor(s, 4);  s += __shfl_xor(s, 2);  s += __shfl_xor(s, 1);
  x = x / s;

  xbuf[wave][lane] = x;
  acc[wave][lane] = 1e-10f;
  if (lane < 16) acc[wave][64 + lane] = 1e-10f;
  __syncthreads();

  // q[t] = p . B[:,t] for t = lane < 16
  float q = 0.0f;
  if (lane < 16) {
#pragma unroll 8
    for (int n = 0; n < 64; ++n) q = fmaf(xbuf[wave][n], Blds[n][lane], q);
  }
  float qm = q;
  qm = fmaxf(qm, __shfl_xor(qm, 8)); qm = fmaxf(qm, __shfl_xor(qm, 4));
  qm = fmaxf(qm, __shfl_xor(qm, 2)); qm = fmaxf(qm, __shfl_xor(qm, 1));
  float e = expf(q - qm);
  float es = e;
  es += __shfl_xor(es, 8); es += __shfl_xor(es, 4);
  es += __shfl_xor(es, 2); es += __shfl_xor(es, 1);
  if (lane < 16) att_lds[wave][lane] = e / es;
  __syncthreads();

  // deterministic serial bucket-accumulate (no atomics)
  if (lane == 0) {
#pragma unroll
    for (int n = 0; n < 16; ++n) {
      int lb = labels[(size_t)batch * 16 + n];
      acc[wave][lb - 1] += att_lds[wave][n];
    }
  }
  __syncthreads();

  float* ob = out + (size_t)batch * 75;
  ob[lane] = logf(acc[wave][lane]);
  if (lane < 11) ob[64 + lane] = logf(acc[wave][64 + lane]);
}

extern "C" void kernel_launch(void* const* d_in, const int* in_sizes, int n_in,
                              void* d_out, int out_size, void* d_ws, size_t ws_size,
                              hipStream_t stream) {
  const float* z      = (const float*)d_in[0];
  const int*   labels = (const int*)d_in[1];
  const float* Kp     = (const float*)d_in[2];
  const float* Lm     = (const float*)d_in[3];
  const float* Bm     = (const float*)d_in[4];
  const float* base   = (const float*)d_in[5];
  float* out = (float*)d_out;

  const int bsz = in_sizes[0] / ZFULL;  // 8192

  const size_t B_bytes = (size_t)256 * 5 * 2 * 64 * 8 * sizeof(ushort);  // 2.62 MB
  int CH = bsz;
  while (CH > 128) {
    size_t A_bytes = (size_t)(CH / 16) * 5 * 2 * 64 * 8 * sizeof(ushort);
    size_t need = B_bytes + A_bytes + (size_t)CH * 4096 * sizeof(float);
    if (need <= ws_size) break;
    CH >>= 1;
  }
  ushort* Bpk = (ushort*)d_ws;
  ushort* Apk = (ushort*)((char*)d_ws + B_bytes);
  size_t A_bytes = (size_t)(CH / 16) * 5 * 2 * 64 * 8 * sizeof(ushort);
  float* rates = (float*)((char*)d_ws + B_bytes + A_bytes);

  pack_B<<<(256 * 640 + 255) / 256, 256, 0, stream>>>(Kp, Lm, Bpk);

  for (int b0 = 0; b0 < bsz; b0 += CH) {
    int a_threads = (CH / 16) * 640;
    pack_A<<<(a_threads + 255) / 256, 256, 0, stream>>>(z, labels, Apk, b0, CH);
    dim3 g(CH / 128, 32);
    gemm_mfma<<<g, 256, 0, stream>>>(Apk, Bpk, base, rates);
    solve_kernel<<<CH / 4, 256, 0, stream>>>(rates, labels, Bm, out, b0);
  }
}

// Round 4
// 202.778 us; speedup vs baseline: 1.4031x; 1.4031x over previous
//
#include <hip/hip_runtime.h>
#include <cstdint>

#define ZFULL 136
#define NCTX 16
#define KCLS 75

typedef __bf16 bf16x8 __attribute__((ext_vector_type(8)));
typedef float f32x4 __attribute__((ext_vector_type(4)));

__device__ __forceinline__ ushort bf16_rne(float v) {
  uint32_t u = __float_as_uint(v);
  return (ushort)((u + 0x7fffu + ((u >> 16) & 1u)) >> 16);
}

__device__ __forceinline__ float rdlane(float v, int l) {
  return __int_as_float(__builtin_amdgcn_readlane(__float_as_int(v), l));
}

// ---- pack A: [CH/16 m_tiles][5 k_tiles][2 h][64 lane][8 j] ushorts (bf16) ----
__global__ __launch_bounds__(256) void pack_A(const float* __restrict__ z,
                                              const int* __restrict__ labels,
                                              ushort* __restrict__ Apk,
                                              int b0, int CH) {
  int idx = blockIdx.x * 256 + threadIdx.x;  // (mt,kt,h,lane)
  int lane = idx & 63;
  int h = (idx >> 6) & 1;
  int kt = (idx >> 7) % 5;
  int mt = idx / 640;
  if (mt >= CH / 16) return;
  int m = b0 + mt * 16 + (lane & 15);
  int kbase = kt * 32 + (lane >> 4) * 8;
  ushort o[8];
#pragma unroll
  for (int j = 0; j < 8; ++j) {
    int k = kbase + j;
    float v = 0.0f;
    if (k < ZFULL) v = z[(size_t)m * ZFULL + k];
    else if (k < ZFULL + NCTX) v = (float)labels[(size_t)m * NCTX + (k - ZFULL)];
    ushort hi = bf16_rne(v);
    if (h == 0) o[j] = hi;
    else {
      float fhi = __uint_as_float((uint32_t)hi << 16);
      o[j] = bf16_rne(v - fhi);
    }
  }
  uint4 w;
  w.x = (uint32_t)o[0] | ((uint32_t)o[1] << 16);
  w.y = (uint32_t)o[2] | ((uint32_t)o[3] << 16);
  w.z = (uint32_t)o[4] | ((uint32_t)o[5] << 16);
  w.w = (uint32_t)o[6] | ((uint32_t)o[7] << 16);
  *(uint4*)(Apk + (size_t)idx * 8) = w;
}

// ---- pack B: [256 n_tiles][5 k_tiles][2 h][64 lane][8 j] ushorts (bf16) ----
__global__ __launch_bounds__(256) void pack_B(const float* __restrict__ Kp,
                                              const float* __restrict__ Lm,
                                              ushort* __restrict__ Bpk) {
  int idx = blockIdx.x * 256 + threadIdx.x;
  int lane = idx & 63;
  int h = (idx >> 6) & 1;
  int kt = (idx >> 7) % 5;
  int nt = idx / 640;
  if (nt >= 256) return;
  int n = nt * 16 + (lane & 15);
  int kbase = kt * 32 + (lane >> 4) * 8;
  ushort o[8];
#pragma unroll
  for (int j = 0; j < 8; ++j) {
    int k = kbase + j;
    float v = 0.0f;
    if (k < ZFULL) v = Kp[(size_t)n * ZFULL + k];
    else if (k < ZFULL + NCTX) v = Lm[(size_t)n * NCTX + (k - ZFULL)];
    ushort hi = bf16_rne(v);
    if (h == 0) o[j] = hi;
    else {
      float fhi = __uint_as_float((uint32_t)hi << 16);
      o[j] = bf16_rne(v - fhi);
    }
  }
  uint4 w;
  w.x = (uint32_t)o[0] | ((uint32_t)o[1] << 16);
  w.y = (uint32_t)o[2] | ((uint32_t)o[3] << 16);
  w.z = (uint32_t)o[4] | ((uint32_t)o[5] << 16);
  w.w = (uint32_t)o[6] | ((uint32_t)o[7] << 16);
  *(uint4*)(Bpk + (size_t)idx * 8) = w;
}

// ---- split-bf16 MFMA GEMM, 128x128 block tile, no LDS (L2-resident packed operands) ----
__global__ __launch_bounds__(256) void gemm_mfma(const ushort* __restrict__ Apk,
                                                 const ushort* __restrict__ Bpk,
                                                 const float* __restrict__ base_log,
                                                 float* __restrict__ rates) {
  const int tid = threadIdx.x;
  const int lane = tid & 63;
  const int w = tid >> 6;
  const int wm = w & 1, wn = w >> 1;
  const int m_tile0 = blockIdx.x * 8 + wm * 4;
  const int n_tile0 = blockIdx.y * 8 + wn * 4;

  f32x4 acc[4][4] = {};

#pragma unroll
  for (int kt = 0; kt < 5; ++kt) {
    bf16x8 ah[4], al[4], bh[4], bl[4];
#pragma unroll
    for (int mt = 0; mt < 4; ++mt) {
      size_t off = (((size_t)(m_tile0 + mt) * 5 + kt) * 128 + lane) * 8;
      ah[mt] = *(const bf16x8*)(Apk + off);
      al[mt] = *(const bf16x8*)(Apk + off + 512);
    }
#pragma unroll
    for (int nt = 0; nt < 4; ++nt) {
      size_t off = (((size_t)(n_tile0 + nt) * 5 + kt) * 128 + lane) * 8;
      bh[nt] = *(const bf16x8*)(Bpk + off);
      bl[nt] = *(const bf16x8*)(Bpk + off + 512);
    }
#pragma unroll
    for (int mt = 0; mt < 4; ++mt)
#pragma unroll
      for (int nt = 0; nt < 4; ++nt) {
        acc[mt][nt] = __builtin_amdgcn_mfma_f32_16x16x32_bf16(ah[mt], bh[nt], acc[mt][nt], 0, 0, 0);
        acc[mt][nt] = __builtin_amdgcn_mfma_f32_16x16x32_bf16(ah[mt], bl[nt], acc[mt][nt], 0, 0, 0);
        acc[mt][nt] = __builtin_amdgcn_mfma_f32_16x16x32_bf16(al[mt], bh[nt], acc[mt][nt], 0, 0, 0);
      }
  }

  const int col_l = lane & 15;
  const int row_l = (lane >> 4) * 4;
#pragma unroll
  for (int mt = 0; mt < 4; ++mt) {
#pragma unroll
    for (int nt = 0; nt < 4; ++nt) {
      int n = (n_tile0 + nt) * 16 + col_l;
      int i = n >> 6, j = n & 63;
      float bse = base_log[n];
#pragma unroll
      for (int r = 0; r < 4; ++r) {
        int m = (m_tile0 + mt) * 16 + row_l + r;
        float v = acc[mt][nt][r] + bse;
        v = fminf(fmaxf(v, -15.0f), 3.0f);
        float e = (i == j) ? 0.0f : expf(v);
        rates[(size_t)m * 4096 + n] = e;
      }
    }
  }
}

// ===== statically-unrolled Gauss-Jordan (readlane broadcasts, no back-sub) =====
template <int K>
struct JD {
  static __device__ __forceinline__ void run(float (&a)[64]) {
    float piv = rdlane(a[K], K);
    float rp = __builtin_amdgcn_rcpf(piv);
    a[K] *= rp;  // row K now has exact 1.0 at column K (on lane K)
#pragma unroll
    for (int i = 0; i < 64; ++i) {
      if (i == K) continue;
      float c = rdlane(a[i], K);   // M[i][K], broadcast from lane K via VALU
      a[i] = fmaf(-c, a[K], a[i]);
    }
    JD<K + 1>::run(a);
  }
};
template <>
struct JD<63> {
  static __device__ __forceinline__ void run(float (&)[64]) {}
};

// ---- solve + attention + logits: one wave per batch, lane = column ----
__global__ __launch_bounds__(256) void solve_kernel(const float* __restrict__ rates,
                                                    const int* __restrict__ labels,
                                                    const float* __restrict__ Bm,
                                                    float* __restrict__ out,
                                                    int b0) {
  __shared__ float Blds[64][16];
  __shared__ float xbuf[4][64];
  __shared__ float att_lds[4][16];
  __shared__ float acc[4][80];

  const int tid = threadIdx.x;
  for (int idx = tid; idx < 1024; idx += 256)
    Blds[idx >> 4][idx & 15] = Bm[idx];

  const int wave = tid >> 6;
  const int lane = tid & 63;
  const int batch = b0 + blockIdx.x * 4 + wave;
  const float* R = rates + (size_t)(blockIdx.x * 4 + wave) * 4096;

  // lane holds column `lane`: a[i] = K[i][lane]
  float a[64];
#pragma unroll
  for (int i = 0; i < 64; ++i) a[i] = R[i * 64 + lane];

  float cs = 0.0f;  // col_sum over all rows (diag entry is 0 from GEMM)
#pragma unroll
  for (int i = 0; i < 64; ++i) cs += a[i];
#pragma unroll
  for (int i = 0; i < 63; ++i) a[i] = (lane == i) ? -cs : a[i];
  a[63] = 1.0f;  // normalization row

  // Gauss-Jordan, pivots 0..62 (no pivoting: leading block column-diag-dominant).
  // b = e_63 is untouched by these steps (b[k]=0 for every pivot row k<63).
  JD<0>::run(a);

  // After diagonalization of columns 0..62 (unit diag):
  //   row 63:  M[63][63] * x63 = 1
  //   row i :  x_i = -M[i][63] * x63   — column 63 lives entirely in lane 63.
  if (lane == 63) {
    float x63 = 1.0f / a[63];
    float v[64];
#pragma unroll
    for (int i = 0; i < 63; ++i) v[i] = fmaxf(-a[i] * x63, 0.0f);
    v[63] = fmaxf(x63, 0.0f);
    float s = 0.0f;
#pragma unroll
    for (int i = 0; i < 64; ++i) s += v[i];
    float rs = 1.0f / s;
#pragma unroll
    for (int i = 0; i < 64; ++i) xbuf[wave][i] = v[i] * rs;
  }

  if (lane < 16) {
    acc[wave][lane] = 1e-10f;
    acc[wave][16 + lane] = 1e-10f;
    acc[wave][32 + lane] = 1e-10f;
    acc[wave][48 + lane] = 1e-10f;
    if (lane < 16) acc[wave][64 + lane] = 1e-10f;
  }
  __syncthreads();

  // q[t] = p . B[:,t] for t = lane < 16
  float q = 0.0f;
  if (lane < 16) {
#pragma unroll 8
    for (int n = 0; n < 64; ++n) q = fmaf(xbuf[wave][n], Blds[n][lane], q);
  }
  float qm = q;
  qm = fmaxf(qm, __shfl_xor(qm, 8)); qm = fmaxf(qm, __shfl_xor(qm, 4));
  qm = fmaxf(qm, __shfl_xor(qm, 2)); qm = fmaxf(qm, __shfl_xor(qm, 1));
  float e = expf(q - qm);
  float es = e;
  es += __shfl_xor(es, 8); es += __shfl_xor(es, 4);
  es += __shfl_xor(es, 2); es += __shfl_xor(es, 1);
  if (lane < 16) att_lds[wave][lane] = e / es;
  __syncthreads();

  // deterministic serial bucket-accumulate (no atomics)
  if (lane == 0) {
#pragma unroll
    for (int n = 0; n < 16; ++n) {
      int lb = labels[(size_t)batch * 16 + n];
      acc[wave][lb - 1] += att_lds[wave][n];
    }
  }
  __syncthreads();

  float* ob = out + (size_t)batch * 75;
  ob[lane] = logf(acc[wave][lane]);
  if (lane < 11) ob[64 + lane] = logf(acc[wave][64 + lane]);
}

extern "C" void kernel_launch(void* const* d_in, const int* in_sizes, int n_in,
                              void* d_out, int out_size, void* d_ws, size_t ws_size,
                              hipStream_t stream) {
  const float* z      = (const float*)d_in[0];
  const int*   labels = (const int*)d_in[1];
  const float* Kp     = (const float*)d_in[2];
  const float* Lm     = (const float*)d_in[3];
  const float* Bm     = (const float*)d_in[4];
  const float* base   = (const float*)d_in[5];
  float* out = (float*)d_out;

  const int bsz = in_sizes[0] / ZFULL;  // 8192

  const size_t B_bytes = (size_t)256 * 5 * 2 * 64 * 8 * sizeof(ushort);  // 2.62 MB
  int CH = bsz;
  while (CH > 128) {
    size_t A_bytes = (size_t)(CH / 16) * 5 * 2 * 64 * 8 * sizeof(ushort);
    size_t need = B_bytes + A_bytes + (size_t)CH * 4096 * sizeof(float);
    if (need <= ws_size) break;
    CH >>= 1;
  }
  ushort* Bpk = (ushort*)d_ws;
  ushort* Apk = (ushort*)((char*)d_ws + B_bytes);
  size_t A_bytes = (size_t)(CH / 16) * 5 * 2 * 64 * 8 * sizeof(ushort);
  float* rates = (float*)((char*)d_ws + B_bytes + A_bytes);

  pack_B<<<(256 * 640 + 255) / 256, 256, 0, stream>>>(Kp, Lm, Bpk);

  for (int b0 = 0; b0 < bsz; b0 += CH) {
    int a_threads = (CH / 16) * 640;
    pack_A<<<(a_threads + 255) / 256, 256, 0, stream>>>(z, labels, Apk, b0, CH);
    dim3 g(CH / 128, 32);
    gemm_mfma<<<g, 256, 0, stream>>>(Apk, Bpk, base, rates);
    solve_kernel<<<CH / 4, 256, 0, stream>>>(rates, labels, Bm, out, b0);
  }
}

// Round 5
// 146.215 us; speedup vs baseline: 1.9460x; 1.3868x over previous
//
#include <hip/hip_runtime.h>
#include <cstdint>

#define ZFULL 136
#define NCTX 16
#define KCLS 75

typedef __bf16 bf16x8 __attribute__((ext_vector_type(8)));
typedef float f32x4 __attribute__((ext_vector_type(4)));

__device__ __forceinline__ ushort bf16_rne(float v) {
  uint32_t u = __float_as_uint(v);
  return (ushort)((u + 0x7fffu + ((u >> 16) & 1u)) >> 16);
}

__device__ __forceinline__ float rdlane(float v, int l) {
  return __int_as_float(__builtin_amdgcn_readlane(__float_as_int(v), l));
}

// ---- pack A: [CH/16 m_tiles][5 k_tiles][2 h][64 lane][8 j] ushorts (bf16) ----
__global__ __launch_bounds__(256) void pack_A(const float* __restrict__ z,
                                              const int* __restrict__ labels,
                                              ushort* __restrict__ Apk,
                                              int b0, int CH) {
  int idx = blockIdx.x * 256 + threadIdx.x;  // (mt,kt,h,lane)
  int lane = idx & 63;
  int h = (idx >> 6) & 1;
  int kt = (idx >> 7) % 5;
  int mt = idx / 640;
  if (mt >= CH / 16) return;
  int m = b0 + mt * 16 + (lane & 15);
  int kbase = kt * 32 + (lane >> 4) * 8;
  ushort o[8];
#pragma unroll
  for (int j = 0; j < 8; ++j) {
    int k = kbase + j;
    float v = 0.0f;
    if (k < ZFULL) v = z[(size_t)m * ZFULL + k];
    else if (k < ZFULL + NCTX) v = (float)labels[(size_t)m * NCTX + (k - ZFULL)];
    ushort hi = bf16_rne(v);
    if (h == 0) o[j] = hi;
    else {
      float fhi = __uint_as_float((uint32_t)hi << 16);
      o[j] = bf16_rne(v - fhi);
    }
  }
  uint4 w;
  w.x = (uint32_t)o[0] | ((uint32_t)o[1] << 16);
  w.y = (uint32_t)o[2] | ((uint32_t)o[3] << 16);
  w.z = (uint32_t)o[4] | ((uint32_t)o[5] << 16);
  w.w = (uint32_t)o[6] | ((uint32_t)o[7] << 16);
  *(uint4*)(Apk + (size_t)idx * 8) = w;
}

// ---- pack B: [256 n_tiles][5 k_tiles][2 h][64 lane][8 j] ushorts (bf16) ----
__global__ __launch_bounds__(256) void pack_B(const float* __restrict__ Kp,
                                              const float* __restrict__ Lm,
                                              ushort* __restrict__ Bpk) {
  int idx = blockIdx.x * 256 + threadIdx.x;
  int lane = idx & 63;
  int h = (idx >> 6) & 1;
  int kt = (idx >> 7) % 5;
  int nt = idx / 640;
  if (nt >= 256) return;
  int n = nt * 16 + (lane & 15);
  int kbase = kt * 32 + (lane >> 4) * 8;
  ushort o[8];
#pragma unroll
  for (int j = 0; j < 8; ++j) {
    int k = kbase + j;
    float v = 0.0f;
    if (k < ZFULL) v = Kp[(size_t)n * ZFULL + k];
    else if (k < ZFULL + NCTX) v = Lm[(size_t)n * NCTX + (k - ZFULL)];
    ushort hi = bf16_rne(v);
    if (h == 0) o[j] = hi;
    else {
      float fhi = __uint_as_float((uint32_t)hi << 16);
      o[j] = bf16_rne(v - fhi);
    }
  }
  uint4 w;
  w.x = (uint32_t)o[0] | ((uint32_t)o[1] << 16);
  w.y = (uint32_t)o[2] | ((uint32_t)o[3] << 16);
  w.z = (uint32_t)o[4] | ((uint32_t)o[5] << 16);
  w.w = (uint32_t)o[6] | ((uint32_t)o[7] << 16);
  *(uint4*)(Bpk + (size_t)idx * 8) = w;
}

// ---- split-bf16 MFMA GEMM, 128x128 block tile, no LDS (L2-resident packed operands) ----
__global__ __launch_bounds__(256) void gemm_mfma(const ushort* __restrict__ Apk,
                                                 const ushort* __restrict__ Bpk,
                                                 const float* __restrict__ base_log,
                                                 float* __restrict__ rates) {
  const int tid = threadIdx.x;
  const int lane = tid & 63;
  const int w = tid >> 6;
  const int wm = w & 1, wn = w >> 1;
  const int m_tile0 = blockIdx.x * 8 + wm * 4;
  const int n_tile0 = blockIdx.y * 8 + wn * 4;

  f32x4 acc[4][4] = {};

#pragma unroll
  for (int kt = 0; kt < 5; ++kt) {
    bf16x8 ah[4], al[4], bh[4], bl[4];
#pragma unroll
    for (int mt = 0; mt < 4; ++mt) {
      size_t off = (((size_t)(m_tile0 + mt) * 5 + kt) * 128 + lane) * 8;
      ah[mt] = *(const bf16x8*)(Apk + off);
      al[mt] = *(const bf16x8*)(Apk + off + 512);
    }
#pragma unroll
    for (int nt = 0; nt < 4; ++nt) {
      size_t off = (((size_t)(n_tile0 + nt) * 5 + kt) * 128 + lane) * 8;
      bh[nt] = *(const bf16x8*)(Bpk + off);
      bl[nt] = *(const bf16x8*)(Bpk + off + 512);
    }
#pragma unroll
    for (int mt = 0; mt < 4; ++mt)
#pragma unroll
      for (int nt = 0; nt < 4; ++nt) {
        acc[mt][nt] = __builtin_amdgcn_mfma_f32_16x16x32_bf16(ah[mt], bh[nt], acc[mt][nt], 0, 0, 0);
        acc[mt][nt] = __builtin_amdgcn_mfma_f32_16x16x32_bf16(ah[mt], bl[nt], acc[mt][nt], 0, 0, 0);
        acc[mt][nt] = __builtin_amdgcn_mfma_f32_16x16x32_bf16(al[mt], bh[nt], acc[mt][nt], 0, 0, 0);
      }
  }

  const int col_l = lane & 15;
  const int row_l = (lane >> 4) * 4;
#pragma unroll
  for (int mt = 0; mt < 4; ++mt) {
#pragma unroll
    for (int nt = 0; nt < 4; ++nt) {
      int n = (n_tile0 + nt) * 16 + col_l;
      int i = n >> 6, j = n & 63;
      float bse = base_log[n];
#pragma unroll
      for (int r = 0; r < 4; ++r) {
        int m = (m_tile0 + mt) * 16 + row_l + r;
        float v = acc[mt][nt][r] + bse;
        v = fminf(fmaxf(v, -15.0f), 3.0f);
        float e = (i == j) ? 0.0f : expf(v);
        rates[(size_t)m * 4096 + n] = e;
      }
    }
  }
}

// ===== row-layout Gauss-Jordan: lane = row, regs = columns =====
// Per pivot K: multiplier is lane-local; broadcast pivot ROW via readlane,
// update only columns j>K (shrinking register loop). All rows update in
// parallel (GJ costs same as LU in this layout).
template <int K>
struct GJ {
  static __device__ __forceinline__ void run(float (&a)[64], float& d, int lane) {
    float piv = rdlane(a[K], K);
    float rp = __builtin_amdgcn_rcpf(piv);
    bool isk = (lane == K);
    float m = isk ? 0.0f : a[K] * rp;
    d = isk ? piv : d;
#pragma unroll
    for (int j = K + 1; j < 64; ++j) {
      float p = rdlane(a[j], K);
      a[j] = fmaf(-m, p, a[j]);
    }
    GJ<K + 1>::run(a, d, lane);
  }
};
template <>
struct GJ<63> {
  static __device__ __forceinline__ void run(float (&)[64], float&, int) {}
};

// ---- solve + attention + logits: one wave per batch, lane = ROW ----
__global__ __launch_bounds__(256) void solve_kernel(const float* __restrict__ rates,
                                                    const int* __restrict__ labels,
                                                    const float* __restrict__ Bm,
                                                    float* __restrict__ out,
                                                    int b0) {
  __shared__ float Blds[64][16];
  __shared__ float xbuf[4][64];
  __shared__ float att_lds[4][16];
  __shared__ float acc[4][80];

  const int tid = threadIdx.x;
  for (int idx = tid; idx < 1024; idx += 256)
    Blds[idx >> 4][idx & 15] = Bm[idx];

  const int wave = tid >> 6;
  const int lane = tid & 63;
  const int batch = b0 + blockIdx.x * 4 + wave;
  const float* R = rates + (size_t)(blockIdx.x * 4 + wave) * 4096 + (size_t)lane * 64;

  // lane holds ROW `lane`: a[j] = rates[lane][j] (diag entries are 0)
  float a[64];
#pragma unroll
  for (int j4 = 0; j4 < 16; ++j4) {
    float4 v = *(const float4*)(R + j4 * 4);
    a[j4 * 4 + 0] = v.x;
    a[j4 * 4 + 1] = v.y;
    a[j4 * 4 + 2] = v.z;
    a[j4 * 4 + 3] = v.w;
  }

  // ---- transpose-reduce: cs (on lane c) = sum over rows of column c ----
  float s32[32];
  {
    bool hi = (lane & 32) != 0;
#pragma unroll
    for (int j = 0; j < 32; ++j) {
      float keep = hi ? a[j + 32] : a[j];
      float send = hi ? a[j] : a[j + 32];
      s32[j] = keep + __shfl_xor(send, 32);
    }
  }
  float s16[16];
  {
    bool hi = (lane & 16) != 0;
#pragma unroll
    for (int j = 0; j < 16; ++j) {
      float keep = hi ? s32[j + 16] : s32[j];
      float send = hi ? s32[j] : s32[j + 16];
      s16[j] = keep + __shfl_xor(send, 16);
    }
  }
  float s8[8];
  {
    bool hi = (lane & 8) != 0;
#pragma unroll
    for (int j = 0; j < 8; ++j) {
      float keep = hi ? s16[j + 8] : s16[j];
      float send = hi ? s16[j] : s16[j + 8];
      s8[j] = keep + __shfl_xor(send, 8);
    }
  }
  float s4[4];
  {
    bool hi = (lane & 4) != 0;
#pragma unroll
    for (int j = 0; j < 4; ++j) {
      float keep = hi ? s8[j + 4] : s8[j];
      float send = hi ? s8[j] : s8[j + 4];
      s4[j] = keep + __shfl_xor(send, 4);
    }
  }
  float s2[2];
  {
    bool hi = (lane & 2) != 0;
#pragma unroll
    for (int j = 0; j < 2; ++j) {
      float keep = hi ? s4[j + 2] : s4[j];
      float send = hi ? s4[j] : s4[j + 2];
      s2[j] = keep + __shfl_xor(send, 2);
    }
  }
  float cs;
  {
    bool hi = (lane & 1) != 0;
    float keep = hi ? s2[1] : s2[0];
    float send = hi ? s2[0] : s2[1];
    cs = keep + __shfl_xor(send, 1);
  }

  // ---- build K_mod: diag = -colsum (rows 0..62); row 63 = all ones ----
  const bool is63 = (lane == 63);
  const float ncs = -cs;
#pragma unroll
  for (int j = 0; j < 64; ++j) {
    float v = (lane == j) ? ncs : a[j];
    a[j] = is63 ? 1.0f : v;
  }

  // ---- Gauss-Jordan pivots 0..62 (no pivoting; col-diag-dominant). b=e63 untouched. ----
  float d = 1.0f;  // lane i<63 ends with its pivot value; lane 63 unused
  GJ<0>::run(a, d, lane);

  // row i<63:  d_i*x_i + a[63]*x63 = 0 ;  row 63: a[63]*x63 = 1
  float m6363 = rdlane(a[63], 63);
  float x63 = 1.0f / m6363;
  float x = is63 ? x63 : -a[63] * x63 * __builtin_amdgcn_rcpf(d);

  // clip >= 0 and normalize
  x = fmaxf(x, 0.0f);
  float s = x;
  s += __shfl_xor(s, 32); s += __shfl_xor(s, 16); s += __shfl_xor(s, 8);
  s += __shfl_xor(s, 4);  s += __shfl_xor(s, 2);  s += __shfl_xor(s, 1);
  x = x / s;

  xbuf[wave][lane] = x;
  if (lane < 16) {
    acc[wave][lane] = 1e-10f;
    acc[wave][16 + lane] = 1e-10f;
    acc[wave][32 + lane] = 1e-10f;
    acc[wave][48 + lane] = 1e-10f;
    acc[wave][64 + lane] = 1e-10f;
  }
  __syncthreads();

  // q[t] = p . B[:,t] for t = lane < 16
  float q = 0.0f;
  if (lane < 16) {
#pragma unroll 8
    for (int n = 0; n < 64; ++n) q = fmaf(xbuf[wave][n], Blds[n][lane], q);
  }
  float qm = q;
  qm = fmaxf(qm, __shfl_xor(qm, 8)); qm = fmaxf(qm, __shfl_xor(qm, 4));
  qm = fmaxf(qm, __shfl_xor(qm, 2)); qm = fmaxf(qm, __shfl_xor(qm, 1));
  float e = expf(q - qm);
  float es = e;
  es += __shfl_xor(es, 8); es += __shfl_xor(es, 4);
  es += __shfl_xor(es, 2); es += __shfl_xor(es, 1);
  if (lane < 16) att_lds[wave][lane] = e / es;
  __syncthreads();

  // deterministic serial bucket-accumulate (no atomics)
  if (lane == 0) {
#pragma unroll
    for (int n = 0; n < 16; ++n) {
      int lb = labels[(size_t)batch * 16 + n];
      acc[wave][lb - 1] += att_lds[wave][n];
    }
  }
  __syncthreads();

  float* ob = out + (size_t)batch * 75;
  ob[lane] = logf(acc[wave][lane]);
  if (lane < 11) ob[64 + lane] = logf(acc[wave][64 + lane]);
}

extern "C" void kernel_launch(void* const* d_in, const int* in_sizes, int n_in,
                              void* d_out, int out_size, void* d_ws, size_t ws_size,
                              hipStream_t stream) {
  const float* z      = (const float*)d_in[0];
  const int*   labels = (const int*)d_in[1];
  const float* Kp     = (const float*)d_in[2];
  const float* Lm     = (const float*)d_in[3];
  const float* Bm     = (const float*)d_in[4];
  const float* base   = (const float*)d_in[5];
  float* out = (float*)d_out;

  const int bsz = in_sizes[0] / ZFULL;  // 8192

  const size_t B_bytes = (size_t)256 * 5 * 2 * 64 * 8 * sizeof(ushort);  // 2.62 MB
  int CH = bsz;
  while (CH > 128) {
    size_t A_bytes = (size_t)(CH / 16) * 5 * 2 * 64 * 8 * sizeof(ushort);
    size_t need = B_bytes + A_bytes + (size_t)CH * 4096 * sizeof(float);
    if (need <= ws_size) break;
    CH >>= 1;
  }
  ushort* Bpk = (ushort*)d_ws;
  ushort* Apk = (ushort*)((char*)d_ws + B_bytes);
  size_t A_bytes = (size_t)(CH / 16) * 5 * 2 * 64 * 8 * sizeof(ushort);
  float* rates = (float*)((char*)d_ws + B_bytes + A_bytes);

  pack_B<<<(256 * 640 + 255) / 256, 256, 0, stream>>>(Kp, Lm, Bpk);

  for (int b0 = 0; b0 < bsz; b0 += CH) {
    int a_threads = (CH / 16) * 640;
    pack_A<<<(a_threads + 255) / 256, 256, 0, stream>>>(z, labels, Apk, b0, CH);
    dim3 g(CH / 128, 32);
    gemm_mfma<<<g, 256, 0, stream>>>(Apk, Bpk, base, rates);
    solve_kernel<<<CH / 4, 256, 0, stream>>>(rates, labels, Bm, out, b0);
  }
}

// Round 6
// 146.064 us; speedup vs baseline: 1.9480x; 1.0010x over previous
//
#include <hip/hip_runtime.h>
#include <cstdint>

#define ZFULL 136
#define NCTX 16
#define KCLS 75

typedef __bf16 bf16x8 __attribute__((ext_vector_type(8)));
typedef float f32x4 __attribute__((ext_vector_type(4)));

__device__ __forceinline__ ushort bf16_rne(float v) {
  uint32_t u = __float_as_uint(v);
  return (ushort)((u + 0x7fffu + ((u >> 16) & 1u)) >> 16);
}

__device__ __forceinline__ float rdlane(float v, int l) {
  return __int_as_float(__builtin_amdgcn_readlane(__float_as_int(v), l));
}

// ---- pack A: [CH/16 m_tiles][5 k_tiles][2 h][64 lane][8 j] ushorts (bf16) ----
__global__ __launch_bounds__(256) void pack_A(const float* __restrict__ z,
                                              const int* __restrict__ labels,
                                              ushort* __restrict__ Apk,
                                              int b0, int CH) {
  int idx = blockIdx.x * 256 + threadIdx.x;  // (mt,kt,h,lane)
  int lane = idx & 63;
  int h = (idx >> 6) & 1;
  int kt = (idx >> 7) % 5;
  int mt = idx / 640;
  if (mt >= CH / 16) return;
  int m = b0 + mt * 16 + (lane & 15);
  int kbase = kt * 32 + (lane >> 4) * 8;
  ushort o[8];
#pragma unroll
  for (int j = 0; j < 8; ++j) {
    int k = kbase + j;
    float v = 0.0f;
    if (k < ZFULL) v = z[(size_t)m * ZFULL + k];
    else if (k < ZFULL + NCTX) v = (float)labels[(size_t)m * NCTX + (k - ZFULL)];
    ushort hi = bf16_rne(v);
    if (h == 0) o[j] = hi;
    else {
      float fhi = __uint_as_float((uint32_t)hi << 16);
      o[j] = bf16_rne(v - fhi);
    }
  }
  uint4 w;
  w.x = (uint32_t)o[0] | ((uint32_t)o[1] << 16);
  w.y = (uint32_t)o[2] | ((uint32_t)o[3] << 16);
  w.z = (uint32_t)o[4] | ((uint32_t)o[5] << 16);
  w.w = (uint32_t)o[6] | ((uint32_t)o[7] << 16);
  *(uint4*)(Apk + (size_t)idx * 8) = w;
}

// ---- pack B: [256 n_tiles][5 k_tiles][2 h][64 lane][8 j] ushorts (bf16) ----
__global__ __launch_bounds__(256) void pack_B(const float* __restrict__ Kp,
                                              const float* __restrict__ Lm,
                                              ushort* __restrict__ Bpk) {
  int idx = blockIdx.x * 256 + threadIdx.x;
  int lane = idx & 63;
  int h = (idx >> 6) & 1;
  int kt = (idx >> 7) % 5;
  int nt = idx / 640;
  if (nt >= 256) return;
  int n = nt * 16 + (lane & 15);
  int kbase = kt * 32 + (lane >> 4) * 8;
  ushort o[8];
#pragma unroll
  for (int j = 0; j < 8; ++j) {
    int k = kbase + j;
    float v = 0.0f;
    if (k < ZFULL) v = Kp[(size_t)n * ZFULL + k];
    else if (k < ZFULL + NCTX) v = Lm[(size_t)n * NCTX + (k - ZFULL)];
    ushort hi = bf16_rne(v);
    if (h == 0) o[j] = hi;
    else {
      float fhi = __uint_as_float((uint32_t)hi << 16);
      o[j] = bf16_rne(v - fhi);
    }
  }
  uint4 w;
  w.x = (uint32_t)o[0] | ((uint32_t)o[1] << 16);
  w.y = (uint32_t)o[2] | ((uint32_t)o[3] << 16);
  w.z = (uint32_t)o[4] | ((uint32_t)o[5] << 16);
  w.w = (uint32_t)o[6] | ((uint32_t)o[7] << 16);
  *(uint4*)(Bpk + (size_t)idx * 8) = w;
}

// ---- split-bf16 MFMA GEMM, 128x128 block tile, no LDS (L2-resident packed operands) ----
__global__ __launch_bounds__(256) void gemm_mfma(const ushort* __restrict__ Apk,
                                                 const ushort* __restrict__ Bpk,
                                                 const float* __restrict__ base_log,
                                                 float* __restrict__ rates) {
  const int tid = threadIdx.x;
  const int lane = tid & 63;
  const int w = tid >> 6;
  const int wm = w & 1, wn = w >> 1;
  const int m_tile0 = blockIdx.x * 8 + wm * 4;
  const int n_tile0 = blockIdx.y * 8 + wn * 4;

  f32x4 acc[4][4] = {};

#pragma unroll
  for (int kt = 0; kt < 5; ++kt) {
    bf16x8 ah[4], al[4], bh[4], bl[4];
#pragma unroll
    for (int mt = 0; mt < 4; ++mt) {
      size_t off = (((size_t)(m_tile0 + mt) * 5 + kt) * 128 + lane) * 8;
      ah[mt] = *(const bf16x8*)(Apk + off);
      al[mt] = *(const bf16x8*)(Apk + off + 512);
    }
#pragma unroll
    for (int nt = 0; nt < 4; ++nt) {
      size_t off = (((size_t)(n_tile0 + nt) * 5 + kt) * 128 + lane) * 8;
      bh[nt] = *(const bf16x8*)(Bpk + off);
      bl[nt] = *(const bf16x8*)(Bpk + off + 512);
    }
#pragma unroll
    for (int mt = 0; mt < 4; ++mt)
#pragma unroll
      for (int nt = 0; nt < 4; ++nt) {
        acc[mt][nt] = __builtin_amdgcn_mfma_f32_16x16x32_bf16(ah[mt], bh[nt], acc[mt][nt], 0, 0, 0);
        acc[mt][nt] = __builtin_amdgcn_mfma_f32_16x16x32_bf16(ah[mt], bl[nt], acc[mt][nt], 0, 0, 0);
        acc[mt][nt] = __builtin_amdgcn_mfma_f32_16x16x32_bf16(al[mt], bh[nt], acc[mt][nt], 0, 0, 0);
      }
  }

  const int col_l = lane & 15;
  const int row_l = (lane >> 4) * 4;
#pragma unroll
  for (int mt = 0; mt < 4; ++mt) {
#pragma unroll
    for (int nt = 0; nt < 4; ++nt) {
      int n = (n_tile0 + nt) * 16 + col_l;
      int i = n >> 6, j = n & 63;
      float bse = base_log[n];
#pragma unroll
      for (int r = 0; r < 4; ++r) {
        int m = (m_tile0 + mt) * 16 + row_l + r;
        float v = acc[mt][nt][r] + bse;
        v = fminf(fmaxf(v, -15.0f), 3.0f);
        float e = (i == j) ? 0.0f : expf(v);
        rates[(size_t)m * 4096 + n] = e;
      }
    }
  }
}

// ===== row-layout Gauss-Jordan: lane = row, regs = columns =====
template <int K>
struct GJ {
  static __device__ __forceinline__ void run(float (&a)[64], float& d, int lane) {
    float piv = rdlane(a[K], K);
    float rp = __builtin_amdgcn_rcpf(piv);
    bool isk = (lane == K);
    float m = isk ? 0.0f : a[K] * rp;
    d = isk ? piv : d;
#pragma unroll
    for (int j = K + 1; j < 64; ++j) {
      float p = rdlane(a[j], K);
      a[j] = fmaf(-m, p, a[j]);
    }
    GJ<K + 1>::run(a, d, lane);
  }
};
template <>
struct GJ<63> {
  static __device__ __forceinline__ void run(float (&)[64], float&, int) {}
};

// ---- solve + attention + logits: one wave per batch, lane = ROW ----
// __launch_bounds__(256, 3): min 3 waves/EU -> ~168 arch-VGPR budget so a[64]
// lives in architectural VGPRs (not AGPR ping-pong; round-5 showed VGPR=56 +
// ~2x VALU count = accvgpr read/write around every GJ fma).
__global__ __launch_bounds__(256, 3) void solve_kernel(const float* __restrict__ rates,
                                                       const int* __restrict__ labels,
                                                       const float* __restrict__ Bm,
                                                       float* __restrict__ out,
                                                       int b0) {
  __shared__ float Blds[64][16];
  __shared__ float xbuf[4][64];
  __shared__ float att_lds[4][16];
  __shared__ float acc[4][80];

  const int tid = threadIdx.x;
  for (int idx = tid; idx < 1024; idx += 256)
    Blds[idx >> 4][idx & 15] = Bm[idx];

  const int wave = tid >> 6;
  const int lane = tid & 63;
  const int batch = b0 + blockIdx.x * 4 + wave;
  const float* R = rates + (size_t)(blockIdx.x * 4 + wave) * 4096 + (size_t)lane * 64;

  // lane holds ROW `lane`: a[j] = rates[lane][j] (diag entries are 0)
  float a[64];
#pragma unroll
  for (int j4 = 0; j4 < 16; ++j4) {
    float4 v = *(const float4*)(R + j4 * 4);
    a[j4 * 4 + 0] = v.x;
    a[j4 * 4 + 1] = v.y;
    a[j4 * 4 + 2] = v.z;
    a[j4 * 4 + 3] = v.w;
  }

  // ---- transpose-reduce: cs (on lane c) = sum over rows of column c ----
  float s32[32];
  {
    bool hi = (lane & 32) != 0;
#pragma unroll
    for (int j = 0; j < 32; ++j) {
      float keep = hi ? a[j + 32] : a[j];
      float send = hi ? a[j] : a[j + 32];
      s32[j] = keep + __shfl_xor(send, 32);
    }
  }
  float s16[16];
  {
    bool hi = (lane & 16) != 0;
#pragma unroll
    for (int j = 0; j < 16; ++j) {
      float keep = hi ? s32[j + 16] : s32[j];
      float send = hi ? s32[j] : s32[j + 16];
      s16[j] = keep + __shfl_xor(send, 16);
    }
  }
  float s8[8];
  {
    bool hi = (lane & 8) != 0;
#pragma unroll
    for (int j = 0; j < 8; ++j) {
      float keep = hi ? s16[j + 8] : s16[j];
      float send = hi ? s16[j] : s16[j + 8];
      s8[j] = keep + __shfl_xor(send, 8);
    }
  }
  float s4[4];
  {
    bool hi = (lane & 4) != 0;
#pragma unroll
    for (int j = 0; j < 4; ++j) {
      float keep = hi ? s8[j + 4] : s8[j];
      float send = hi ? s8[j] : s8[j + 4];
      s4[j] = keep + __shfl_xor(send, 4);
    }
  }
  float s2[2];
  {
    bool hi = (lane & 2) != 0;
#pragma unroll
    for (int j = 0; j < 2; ++j) {
      float keep = hi ? s4[j + 2] : s4[j];
      float send = hi ? s4[j] : s4[j + 2];
      s2[j] = keep + __shfl_xor(send, 2);
    }
  }
  float cs;
  {
    bool hi = (lane & 1) != 0;
    float keep = hi ? s2[1] : s2[0];
    float send = hi ? s2[0] : s2[1];
    cs = keep + __shfl_xor(send, 1);
  }

  // ---- build K_mod: diag = -colsum (rows 0..62); row 63 = all ones ----
  const bool is63 = (lane == 63);
  const float ncs = -cs;
#pragma unroll
  for (int j = 0; j < 64; ++j) {
    float v = (lane == j) ? ncs : a[j];
    a[j] = is63 ? 1.0f : v;
  }

  // ---- Gauss-Jordan pivots 0..62 (no pivoting; col-diag-dominant). b=e63 untouched. ----
  float d = 1.0f;
  GJ<0>::run(a, d, lane);

  // row i<63:  d_i*x_i + a[63]*x63 = 0 ;  row 63: a[63]*x63 = 1
  float m6363 = rdlane(a[63], 63);
  float x63 = 1.0f / m6363;
  float x = is63 ? x63 : -a[63] * x63 * __builtin_amdgcn_rcpf(d);

  // clip >= 0 and normalize
  x = fmaxf(x, 0.0f);
  float s = x;
  s += __shfl_xor(s, 32); s += __shfl_xor(s, 16); s += __shfl_xor(s, 8);
  s += __shfl_xor(s, 4);  s += __shfl_xor(s, 2);  s += __shfl_xor(s, 1);
  x = x / s;

  xbuf[wave][lane] = x;
  if (lane < 16) {
    acc[wave][lane] = 1e-10f;
    acc[wave][16 + lane] = 1e-10f;
    acc[wave][32 + lane] = 1e-10f;
    acc[wave][48 + lane] = 1e-10f;
    acc[wave][64 + lane] = 1e-10f;
  }
  __syncthreads();

  // q[t] = p . B[:,t] for t = lane < 16
  float q = 0.0f;
  if (lane < 16) {
#pragma unroll 8
    for (int n = 0; n < 64; ++n) q = fmaf(xbuf[wave][n], Blds[n][lane], q);
  }
  float qm = q;
  qm = fmaxf(qm, __shfl_xor(qm, 8)); qm = fmaxf(qm, __shfl_xor(qm, 4));
  qm = fmaxf(qm, __shfl_xor(qm, 2)); qm = fmaxf(qm, __shfl_xor(qm, 1));
  float e = expf(q - qm);
  float es = e;
  es += __shfl_xor(es, 8); es += __shfl_xor(es, 4);
  es += __shfl_xor(es, 2); es += __shfl_xor(es, 1);
  if (lane < 16) att_lds[wave][lane] = e / es;
  __syncthreads();

  // deterministic serial bucket-accumulate (no atomics)
  if (lane == 0) {
#pragma unroll
    for (int n = 0; n < 16; ++n) {
      int lb = labels[(size_t)batch * 16 + n];
      acc[wave][lb - 1] += att_lds[wave][n];
    }
  }
  __syncthreads();

  float* ob = out + (size_t)batch * 75;
  ob[lane] = logf(acc[wave][lane]);
  if (lane < 11) ob[64 + lane] = logf(acc[wave][64 + lane]);
}

extern "C" void kernel_launch(void* const* d_in, const int* in_sizes, int n_in,
                              void* d_out, int out_size, void* d_ws, size_t ws_size,
                              hipStream_t stream) {
  const float* z      = (const float*)d_in[0];
  const int*   labels = (const int*)d_in[1];
  const float* Kp     = (const float*)d_in[2];
  const float* Lm     = (const float*)d_in[3];
  const float* Bm     = (const float*)d_in[4];
  const float* base   = (const float*)d_in[5];
  float* out = (float*)d_out;

  const int bsz = in_sizes[0] / ZFULL;  // 8192

  const size_t B_bytes = (size_t)256 * 5 * 2 * 64 * 8 * sizeof(ushort);  // 2.62 MB
  int CH = bsz;
  while (CH > 128) {
    size_t A_bytes = (size_t)(CH / 16) * 5 * 2 * 64 * 8 * sizeof(ushort);
    size_t need = B_bytes + A_bytes + (size_t)CH * 4096 * sizeof(float);
    if (need <= ws_size) break;
    CH >>= 1;
  }
  ushort* Bpk = (ushort*)d_ws;
  ushort* Apk = (ushort*)((char*)d_ws + B_bytes);
  size_t A_bytes = (size_t)(CH / 16) * 5 * 2 * 64 * 8 * sizeof(ushort);
  float* rates = (float*)((char*)d_ws + B_bytes + A_bytes);

  pack_B<<<(256 * 640 + 255) / 256, 256, 0, stream>>>(Kp, Lm, Bpk);

  for (int b0 = 0; b0 < bsz; b0 += CH) {
    int a_threads = (CH / 16) * 640;
    pack_A<<<(a_threads + 255) / 256, 256, 0, stream>>>(z, labels, Apk, b0, CH);
    dim3 g(CH / 128, 32);
    gemm_mfma<<<g, 256, 0, stream>>>(Apk, Bpk, base, rates);
    solve_kernel<<<CH / 4, 256, 0, stream>>>(rates, labels, Bm, out, b0);
  }
}

// Round 7
// 145.111 us; speedup vs baseline: 1.9608x; 1.0066x over previous
//
#include <hip/hip_runtime.h>
#include <cstdint>

#define ZFULL 136
#define NCTX 16
#define KCLS 75

typedef __bf16 bf16x8 __attribute__((ext_vector_type(8)));
typedef float f32x4 __attribute__((ext_vector_type(4)));

__device__ __forceinline__ ushort bf16_rne(float v) {
  uint32_t u = __float_as_uint(v);
  return (ushort)((u + 0x7fffu + ((u >> 16) & 1u)) >> 16);
}

__device__ __forceinline__ float rdlane(float v, int l) {
  return __int_as_float(__builtin_amdgcn_readlane(__float_as_int(v), l));
}

// ---- pack A: [CH/16 m_tiles][5 k_tiles][2 h][64 lane][8 j] ushorts (bf16) ----
__global__ __launch_bounds__(256) void pack_A(const float* __restrict__ z,
                                              const int* __restrict__ labels,
                                              ushort* __restrict__ Apk,
                                              int b0, int CH) {
  int idx = blockIdx.x * 256 + threadIdx.x;  // (mt,kt,h,lane)
  int lane = idx & 63;
  int h = (idx >> 6) & 1;
  int kt = (idx >> 7) % 5;
  int mt = idx / 640;
  if (mt >= CH / 16) return;
  int m = b0 + mt * 16 + (lane & 15);
  int kbase = kt * 32 + (lane >> 4) * 8;
  ushort o[8];
#pragma unroll
  for (int j = 0; j < 8; ++j) {
    int k = kbase + j;
    float v = 0.0f;
    if (k < ZFULL) v = z[(size_t)m * ZFULL + k];
    else if (k < ZFULL + NCTX) v = (float)labels[(size_t)m * NCTX + (k - ZFULL)];
    ushort hi = bf16_rne(v);
    if (h == 0) o[j] = hi;
    else {
      float fhi = __uint_as_float((uint32_t)hi << 16);
      o[j] = bf16_rne(v - fhi);
    }
  }
  uint4 w;
  w.x = (uint32_t)o[0] | ((uint32_t)o[1] << 16);
  w.y = (uint32_t)o[2] | ((uint32_t)o[3] << 16);
  w.z = (uint32_t)o[4] | ((uint32_t)o[5] << 16);
  w.w = (uint32_t)o[6] | ((uint32_t)o[7] << 16);
  *(uint4*)(Apk + (size_t)idx * 8) = w;
}

// ---- pack B: [256 n_tiles][5 k_tiles][2 h][64 lane][8 j] ushorts (bf16) ----
__global__ __launch_bounds__(256) void pack_B(const float* __restrict__ Kp,
                                              const float* __restrict__ Lm,
                                              ushort* __restrict__ Bpk) {
  int idx = blockIdx.x * 256 + threadIdx.x;
  int lane = idx & 63;
  int h = (idx >> 6) & 1;
  int kt = (idx >> 7) % 5;
  int nt = idx / 640;
  if (nt >= 256) return;
  int n = nt * 16 + (lane & 15);
  int kbase = kt * 32 + (lane >> 4) * 8;
  ushort o[8];
#pragma unroll
  for (int j = 0; j < 8; ++j) {
    int k = kbase + j;
    float v = 0.0f;
    if (k < ZFULL) v = Kp[(size_t)n * ZFULL + k];
    else if (k < ZFULL + NCTX) v = Lm[(size_t)n * NCTX + (k - ZFULL)];
    ushort hi = bf16_rne(v);
    if (h == 0) o[j] = hi;
    else {
      float fhi = __uint_as_float((uint32_t)hi << 16);
      o[j] = bf16_rne(v - fhi);
    }
  }
  uint4 w;
  w.x = (uint32_t)o[0] | ((uint32_t)o[1] << 16);
  w.y = (uint32_t)o[2] | ((uint32_t)o[3] << 16);
  w.z = (uint32_t)o[4] | ((uint32_t)o[5] << 16);
  w.w = (uint32_t)o[6] | ((uint32_t)o[7] << 16);
  *(uint4*)(Bpk + (size_t)idx * 8) = w;
}

// ---- split-bf16 MFMA GEMM, 128x128 block tile, no LDS (L2-resident packed operands) ----
__global__ __launch_bounds__(256) void gemm_mfma(const ushort* __restrict__ Apk,
                                                 const ushort* __restrict__ Bpk,
                                                 const float* __restrict__ base_log,
                                                 float* __restrict__ rates) {
  const int tid = threadIdx.x;
  const int lane = tid & 63;
  const int w = tid >> 6;
  const int wm = w & 1, wn = w >> 1;
  const int m_tile0 = blockIdx.x * 8 + wm * 4;
  const int n_tile0 = blockIdx.y * 8 + wn * 4;

  f32x4 acc[4][4] = {};

#pragma unroll
  for (int kt = 0; kt < 5; ++kt) {
    bf16x8 ah[4], al[4], bh[4], bl[4];
#pragma unroll
    for (int mt = 0; mt < 4; ++mt) {
      size_t off = (((size_t)(m_tile0 + mt) * 5 + kt) * 128 + lane) * 8;
      ah[mt] = *(const bf16x8*)(Apk + off);
      al[mt] = *(const bf16x8*)(Apk + off + 512);
    }
#pragma unroll
    for (int nt = 0; nt < 4; ++nt) {
      size_t off = (((size_t)(n_tile0 + nt) * 5 + kt) * 128 + lane) * 8;
      bh[nt] = *(const bf16x8*)(Bpk + off);
      bl[nt] = *(const bf16x8*)(Bpk + off + 512);
    }
#pragma unroll
    for (int mt = 0; mt < 4; ++mt)
#pragma unroll
      for (int nt = 0; nt < 4; ++nt) {
        acc[mt][nt] = __builtin_amdgcn_mfma_f32_16x16x32_bf16(ah[mt], bh[nt], acc[mt][nt], 0, 0, 0);
        acc[mt][nt] = __builtin_amdgcn_mfma_f32_16x16x32_bf16(ah[mt], bl[nt], acc[mt][nt], 0, 0, 0);
        acc[mt][nt] = __builtin_amdgcn_mfma_f32_16x16x32_bf16(al[mt], bh[nt], acc[mt][nt], 0, 0, 0);
      }
  }

  const int col_l = lane & 15;
  const int row_l = (lane >> 4) * 4;
#pragma unroll
  for (int mt = 0; mt < 4; ++mt) {
#pragma unroll
    for (int nt = 0; nt < 4; ++nt) {
      int n = (n_tile0 + nt) * 16 + col_l;
      int i = n >> 6, j = n & 63;
      float bse = base_log[n];
#pragma unroll
      for (int r = 0; r < 4; ++r) {
        int m = (m_tile0 + mt) * 16 + row_l + r;
        float v = acc[mt][nt][r] + bse;
        v = fminf(fmaxf(v, -15.0f), 3.0f);
        float e = (i == j) ? 0.0f : expf(v);
        rates[(size_t)m * 4096 + n] = e;
      }
    }
  }
}

// ===== row-layout Gauss-Jordan: lane = row, regs = columns =====
template <int K>
struct GJ {
  static __device__ __forceinline__ void run(float (&a)[64], float& d, int lane) {
    float piv = rdlane(a[K], K);
    float rp = __builtin_amdgcn_rcpf(piv);
    bool isk = (lane == K);
    float m = isk ? 0.0f : a[K] * rp;
    d = isk ? piv : d;
#pragma unroll
    for (int j = K + 1; j < 64; ++j) {
      float p = rdlane(a[j], K);
      a[j] = fmaf(-m, p, a[j]);
    }
    GJ<K + 1>::run(a, d, lane);
  }
};
template <>
struct GJ<63> {
  static __device__ __forceinline__ void run(float (&)[64], float&, int) {}
};

// ---- solve + attention + logits: one wave per batch ----
// Pass 1 (lane = COLUMN): colsum via 64 coalesced loads -> cs lands in the
// lane that needs it (diag j==lane in the row-layout build). This replaces
// the register transpose-reduce, cutting peak pressure from ~130 to ~76 so
// a[64] stays in arch VGPRs (round 5/6: allocator split 56 arch + 72 AGPR
// and paid an accvgpr move per GJ fma, ~2x instruction inflation).
__global__ __launch_bounds__(256) void solve_kernel(const float* __restrict__ rates,
                                                    const int* __restrict__ labels,
                                                    const float* __restrict__ Bm,
                                                    float* __restrict__ out,
                                                    int b0) {
  __shared__ float Blds[64][16];
  __shared__ float xbuf[4][64];
  __shared__ float att_lds[4][16];
  __shared__ float acc[4][80];

  const int tid = threadIdx.x;
  for (int idx = tid; idx < 1024; idx += 256)
    Blds[idx >> 4][idx & 15] = Bm[idx];

  const int wave = tid >> 6;
  const int lane = tid & 63;
  const int batch = b0 + blockIdx.x * 4 + wave;
  const float* Rb = rates + (size_t)(blockIdx.x * 4 + wave) * 4096;

  // ---- pass 1: cs = colsum of column `lane` (diag entries are 0) ----
  float cs = 0.0f;
#pragma unroll
  for (int i = 0; i < 64; ++i) cs += Rb[i * 64 + lane];

  // ---- pass 2: lane holds ROW `lane`: a[j] = rates[lane][j] (L1/L2 hot) ----
  const float* R = Rb + (size_t)lane * 64;
  float a[64];
#pragma unroll
  for (int j4 = 0; j4 < 16; ++j4) {
    float4 v = *(const float4*)(R + j4 * 4);
    a[j4 * 4 + 0] = v.x;
    a[j4 * 4 + 1] = v.y;
    a[j4 * 4 + 2] = v.z;
    a[j4 * 4 + 3] = v.w;
  }

  // ---- build K_mod: diag = -colsum (rows 0..62); row 63 = all ones ----
  const bool is63 = (lane == 63);
  const float ncs = -cs;
#pragma unroll
  for (int j = 0; j < 64; ++j) {
    float v = (lane == j) ? ncs : a[j];
    a[j] = is63 ? 1.0f : v;
  }

  // ---- Gauss-Jordan pivots 0..62 (no pivoting; col-diag-dominant). b=e63 untouched. ----
  float d = 1.0f;
  GJ<0>::run(a, d, lane);

  // row i<63:  d_i*x_i + a[63]*x63 = 0 ;  row 63: a[63]*x63 = 1
  float m6363 = rdlane(a[63], 63);
  float x63 = 1.0f / m6363;
  float x = is63 ? x63 : -a[63] * x63 * __builtin_amdgcn_rcpf(d);

  // clip >= 0 and normalize
  x = fmaxf(x, 0.0f);
  float s = x;
  s += __shfl_xor(s, 32); s += __shfl_xor(s, 16); s += __shfl_xor(s, 8);
  s += __shfl_xor(s, 4);  s += __shfl_xor(s, 2);  s += __shfl_xor(s, 1);
  x = x / s;

  xbuf[wave][lane] = x;
  if (lane < 16) {
    acc[wave][lane] = 1e-10f;
    acc[wave][16 + lane] = 1e-10f;
    acc[wave][32 + lane] = 1e-10f;
    acc[wave][48 + lane] = 1e-10f;
    acc[wave][64 + lane] = 1e-10f;
  }
  __syncthreads();

  // q[t] = p . B[:,t] for t = lane < 16
  float q = 0.0f;
  if (lane < 16) {
#pragma unroll 8
    for (int n = 0; n < 64; ++n) q = fmaf(xbuf[wave][n], Blds[n][lane], q);
  }
  float qm = q;
  qm = fmaxf(qm, __shfl_xor(qm, 8)); qm = fmaxf(qm, __shfl_xor(qm, 4));
  qm = fmaxf(qm, __shfl_xor(qm, 2)); qm = fmaxf(qm, __shfl_xor(qm, 1));
  float e = expf(q - qm);
  float es = e;
  es += __shfl_xor(es, 8); es += __shfl_xor(es, 4);
  es += __shfl_xor(es, 2); es += __shfl_xor(es, 1);
  if (lane < 16) att_lds[wave][lane] = e / es;
  __syncthreads();

  // deterministic serial bucket-accumulate (no atomics)
  if (lane == 0) {
#pragma unroll
    for (int n = 0; n < 16; ++n) {
      int lb = labels[(size_t)batch * 16 + n];
      acc[wave][lb - 1] += att_lds[wave][n];
    }
  }
  __syncthreads();

  float* ob = out + (size_t)batch * 75;
  ob[lane] = logf(acc[wave][lane]);
  if (lane < 11) ob[64 + lane] = logf(acc[wave][64 + lane]);
}

extern "C" void kernel_launch(void* const* d_in, const int* in_sizes, int n_in,
                              void* d_out, int out_size, void* d_ws, size_t ws_size,
                              hipStream_t stream) {
  const float* z      = (const float*)d_in[0];
  const int*   labels = (const int*)d_in[1];
  const float* Kp     = (const float*)d_in[2];
  const float* Lm     = (const float*)d_in[3];
  const float* Bm     = (const float*)d_in[4];
  const float* base   = (const float*)d_in[5];
  float* out = (float*)d_out;

  const int bsz = in_sizes[0] / ZFULL;  // 8192

  const size_t B_bytes = (size_t)256 * 5 * 2 * 64 * 8 * sizeof(ushort);  // 2.62 MB
  int CH = bsz;
  while (CH > 128) {
    size_t A_bytes = (size_t)(CH / 16) * 5 * 2 * 64 * 8 * sizeof(ushort);
    size_t need = B_bytes + A_bytes + (size_t)CH * 4096 * sizeof(float);
    if (need <= ws_size) break;
    CH >>= 1;
  }
  ushort* Bpk = (ushort*)d_ws;
  ushort* Apk = (ushort*)((char*)d_ws + B_bytes);
  size_t A_bytes = (size_t)(CH / 16) * 5 * 2 * 64 * 8 * sizeof(ushort);
  float* rates = (float*)((char*)d_ws + B_bytes + A_bytes);

  pack_B<<<(256 * 640 + 255) / 256, 256, 0, stream>>>(Kp, Lm, Bpk);

  for (int b0 = 0; b0 < bsz; b0 += CH) {
    int a_threads = (CH / 16) * 640;
    pack_A<<<(a_threads + 255) / 256, 256, 0, stream>>>(z, labels, Apk, b0, CH);
    dim3 g(CH / 128, 32);
    gemm_mfma<<<g, 256, 0, stream>>>(Apk, Bpk, base, rates);
    solve_kernel<<<CH / 4, 256, 0, stream>>>(rates, labels, Bm, out, b0);
  }
}

// Round 8
// 144.667 us; speedup vs baseline: 1.9668x; 1.0031x over previous
//
#include <hip/hip_runtime.h>
#include <cstdint>

#define ZFULL 136
#define NCTX 16
#define KCLS 75

typedef __bf16 bf16x8 __attribute__((ext_vector_type(8)));
typedef float f32x4 __attribute__((ext_vector_type(4)));

__device__ __forceinline__ ushort bf16_rne(float v) {
  uint32_t u = __float_as_uint(v);
  return (ushort)((u + 0x7fffu + ((u >> 16) & 1u)) >> 16);
}

__device__ __forceinline__ float rdlane(float v, int l) {
  return __int_as_float(__builtin_amdgcn_readlane(__float_as_int(v), l));
}

// Pin 16 floats into distinct ARCH VGPRs at this program point (empty asm,
// zero instructions). Applied per GJ step so AGPR placement of a[] would
// cost a copy per element per step -> allocator must keep a[] in arch VGPRs.
#define PIN16(a, b)                                                          \
  asm volatile("" : "+v"(a[b + 0]), "+v"(a[b + 1]), "+v"(a[b + 2]),          \
                    "+v"(a[b + 3]), "+v"(a[b + 4]), "+v"(a[b + 5]),          \
                    "+v"(a[b + 6]), "+v"(a[b + 7]), "+v"(a[b + 8]),          \
                    "+v"(a[b + 9]), "+v"(a[b + 10]), "+v"(a[b + 11]),        \
                    "+v"(a[b + 12]), "+v"(a[b + 13]), "+v"(a[b + 14]),       \
                    "+v"(a[b + 15]))

__device__ __forceinline__ void pin_all(float (&a)[64]) {
  PIN16(a, 0);
  PIN16(a, 16);
  PIN16(a, 32);
  PIN16(a, 48);
}

// ---- pack A: [CH/16 m_tiles][5 k_tiles][2 h][64 lane][8 j] ushorts (bf16) ----
__global__ __launch_bounds__(256) void pack_A(const float* __restrict__ z,
                                              const int* __restrict__ labels,
                                              ushort* __restrict__ Apk,
                                              int b0, int CH) {
  int idx = blockIdx.x * 256 + threadIdx.x;  // (mt,kt,h,lane)
  int lane = idx & 63;
  int h = (idx >> 6) & 1;
  int kt = (idx >> 7) % 5;
  int mt = idx / 640;
  if (mt >= CH / 16) return;
  int m = b0 + mt * 16 + (lane & 15);
  int kbase = kt * 32 + (lane >> 4) * 8;
  ushort o[8];
#pragma unroll
  for (int j = 0; j < 8; ++j) {
    int k = kbase + j;
    float v = 0.0f;
    if (k < ZFULL) v = z[(size_t)m * ZFULL + k];
    else if (k < ZFULL + NCTX) v = (float)labels[(size_t)m * NCTX + (k - ZFULL)];
    ushort hi = bf16_rne(v);
    if (h == 0) o[j] = hi;
    else {
      float fhi = __uint_as_float((uint32_t)hi << 16);
      o[j] = bf16_rne(v - fhi);
    }
  }
  uint4 w;
  w.x = (uint32_t)o[0] | ((uint32_t)o[1] << 16);
  w.y = (uint32_t)o[2] | ((uint32_t)o[3] << 16);
  w.z = (uint32_t)o[4] | ((uint32_t)o[5] << 16);
  w.w = (uint32_t)o[6] | ((uint32_t)o[7] << 16);
  *(uint4*)(Apk + (size_t)idx * 8) = w;
}

// ---- pack B: [256 n_tiles][5 k_tiles][2 h][64 lane][8 j] ushorts (bf16) ----
__global__ __launch_bounds__(256) void pack_B(const float* __restrict__ Kp,
                                              const float* __restrict__ Lm,
                                              ushort* __restrict__ Bpk) {
  int idx = blockIdx.x * 256 + threadIdx.x;
  int lane = idx & 63;
  int h = (idx >> 6) & 1;
  int kt = (idx >> 7) % 5;
  int nt = idx / 640;
  if (nt >= 256) return;
  int n = nt * 16 + (lane & 15);
  int kbase = kt * 32 + (lane >> 4) * 8;
  ushort o[8];
#pragma unroll
  for (int j = 0; j < 8; ++j) {
    int k = kbase + j;
    float v = 0.0f;
    if (k < ZFULL) v = Kp[(size_t)n * ZFULL + k];
    else if (k < ZFULL + NCTX) v = Lm[(size_t)n * NCTX + (k - ZFULL)];
    ushort hi = bf16_rne(v);
    if (h == 0) o[j] = hi;
    else {
      float fhi = __uint_as_float((uint32_t)hi << 16);
      o[j] = bf16_rne(v - fhi);
    }
  }
  uint4 w;
  w.x = (uint32_t)o[0] | ((uint32_t)o[1] << 16);
  w.y = (uint32_t)o[2] | ((uint32_t)o[3] << 16);
  w.z = (uint32_t)o[4] | ((uint32_t)o[5] << 16);
  w.w = (uint32_t)o[6] | ((uint32_t)o[7] << 16);
  *(uint4*)(Bpk + (size_t)idx * 8) = w;
}

// ---- split-bf16 MFMA GEMM, 128x128 block tile, no LDS (L2-resident packed operands) ----
__global__ __launch_bounds__(256) void gemm_mfma(const ushort* __restrict__ Apk,
                                                 const ushort* __restrict__ Bpk,
                                                 const float* __restrict__ base_log,
                                                 float* __restrict__ rates) {
  const int tid = threadIdx.x;
  const int lane = tid & 63;
  const int w = tid >> 6;
  const int wm = w & 1, wn = w >> 1;
  const int m_tile0 = blockIdx.x * 8 + wm * 4;
  const int n_tile0 = blockIdx.y * 8 + wn * 4;

  f32x4 acc[4][4] = {};

#pragma unroll
  for (int kt = 0; kt < 5; ++kt) {
    bf16x8 ah[4], al[4], bh[4], bl[4];
#pragma unroll
    for (int mt = 0; mt < 4; ++mt) {
      size_t off = (((size_t)(m_tile0 + mt) * 5 + kt) * 128 + lane) * 8;
      ah[mt] = *(const bf16x8*)(Apk + off);
      al[mt] = *(const bf16x8*)(Apk + off + 512);
    }
#pragma unroll
    for (int nt = 0; nt < 4; ++nt) {
      size_t off = (((size_t)(n_tile0 + nt) * 5 + kt) * 128 + lane) * 8;
      bh[nt] = *(const bf16x8*)(Bpk + off);
      bl[nt] = *(const bf16x8*)(Bpk + off + 512);
    }
#pragma unroll
    for (int mt = 0; mt < 4; ++mt)
#pragma unroll
      for (int nt = 0; nt < 4; ++nt) {
        acc[mt][nt] = __builtin_amdgcn_mfma_f32_16x16x32_bf16(ah[mt], bh[nt], acc[mt][nt], 0, 0, 0);
        acc[mt][nt] = __builtin_amdgcn_mfma_f32_16x16x32_bf16(ah[mt], bl[nt], acc[mt][nt], 0, 0, 0);
        acc[mt][nt] = __builtin_amdgcn_mfma_f32_16x16x32_bf16(al[mt], bh[nt], acc[mt][nt], 0, 0, 0);
      }
  }

  const int col_l = lane & 15;
  const int row_l = (lane >> 4) * 4;
#pragma unroll
  for (int mt = 0; mt < 4; ++mt) {
#pragma unroll
    for (int nt = 0; nt < 4; ++nt) {
      int n = (n_tile0 + nt) * 16 + col_l;
      int i = n >> 6, j = n & 63;
      float bse = base_log[n];
#pragma unroll
      for (int r = 0; r < 4; ++r) {
        int m = (m_tile0 + mt) * 16 + row_l + r;
        float v = acc[mt][nt][r] + bse;
        v = fminf(fmaxf(v, -15.0f), 3.0f);
        float e = (i == j) ? 0.0f : expf(v);
        rates[(size_t)m * 4096 + n] = e;
      }
    }
  }
}

// ===== row-layout Gauss-Jordan: lane = row, regs = columns =====
// Per step: pin a[] into arch VGPRs + sched_barrier so the scheduler cannot
// create cross-step pressure spikes and the allocator cannot park a[] in
// AGPRs (rounds 5-7: AGPR ping-pong doubled the VALU instruction count).
template <int K>
struct GJ {
  static __device__ __forceinline__ void run(float (&a)[64], float& d, int lane) {
    float piv = rdlane(a[K], K);
    float rp = __builtin_amdgcn_rcpf(piv);
    bool isk = (lane == K);
    float m = isk ? 0.0f : a[K] * rp;
    d = isk ? piv : d;
#pragma unroll
    for (int j = K + 1; j < 64; ++j) {
      float p = rdlane(a[j], K);
      a[j] = fmaf(-m, p, a[j]);
    }
    pin_all(a);
    __builtin_amdgcn_sched_barrier(0);
    GJ<K + 1>::run(a, d, lane);
  }
};
template <>
struct GJ<63> {
  static __device__ __forceinline__ void run(float (&)[64], float&, int) {}
};

// ---- solve + attention + logits: one wave per batch ----
__global__ __launch_bounds__(256) void solve_kernel(const float* __restrict__ rates,
                                                    const int* __restrict__ labels,
                                                    const float* __restrict__ Bm,
                                                    float* __restrict__ out,
                                                    int b0) {
  __shared__ float Blds[64][16];
  __shared__ float xbuf[4][64];
  __shared__ float att_lds[4][16];
  __shared__ float acc[4][80];

  const int tid = threadIdx.x;
  for (int idx = tid; idx < 1024; idx += 256)
    Blds[idx >> 4][idx & 15] = Bm[idx];

  const int wave = tid >> 6;
  const int lane = tid & 63;
  const int batch = b0 + blockIdx.x * 4 + wave;
  const float* Rb = rates + (size_t)(blockIdx.x * 4 + wave) * 4096;

  // ---- pass 1: cs = colsum of column `lane` (diag entries are 0) ----
  float cs = 0.0f;
#pragma unroll
  for (int i = 0; i < 64; ++i) cs += Rb[i * 64 + lane];

  // ---- pass 2: lane holds ROW `lane`: a[j] = rates[lane][j] (L1/L2 hot) ----
  const float* R = Rb + (size_t)lane * 64;
  float a[64];
#pragma unroll
  for (int j4 = 0; j4 < 16; ++j4) {
    float4 v = *(const float4*)(R + j4 * 4);
    a[j4 * 4 + 0] = v.x;
    a[j4 * 4 + 1] = v.y;
    a[j4 * 4 + 2] = v.z;
    a[j4 * 4 + 3] = v.w;
  }

  // ---- build K_mod: diag = -colsum (rows 0..62); row 63 = all ones ----
  const bool is63 = (lane == 63);
  const float ncs = -cs;
#pragma unroll
  for (int j = 0; j < 64; ++j) {
    float v = (lane == j) ? ncs : a[j];
    a[j] = is63 ? 1.0f : v;
  }
  pin_all(a);

  // ---- Gauss-Jordan pivots 0..62 (no pivoting; col-diag-dominant). b=e63 untouched. ----
  float d = 1.0f;
  GJ<0>::run(a, d, lane);

  // row i<63:  d_i*x_i + a[63]*x63 = 0 ;  row 63: a[63]*x63 = 1
  float m6363 = rdlane(a[63], 63);
  float x63 = 1.0f / m6363;
  float x = is63 ? x63 : -a[63] * x63 * __builtin_amdgcn_rcpf(d);

  // clip >= 0 and normalize
  x = fmaxf(x, 0.0f);
  float s = x;
  s += __shfl_xor(s, 32); s += __shfl_xor(s, 16); s += __shfl_xor(s, 8);
  s += __shfl_xor(s, 4);  s += __shfl_xor(s, 2);  s += __shfl_xor(s, 1);
  x = x / s;

  xbuf[wave][lane] = x;
  if (lane < 16) {
    acc[wave][lane] = 1e-10f;
    acc[wave][16 + lane] = 1e-10f;
    acc[wave][32 + lane] = 1e-10f;
    acc[wave][48 + lane] = 1e-10f;
    acc[wave][64 + lane] = 1e-10f;
  }
  __syncthreads();

  // q[t] = p . B[:,t] for t = lane < 16
  float q = 0.0f;
  if (lane < 16) {
#pragma unroll 8
    for (int n = 0; n < 64; ++n) q = fmaf(xbuf[wave][n], Blds[n][lane], q);
  }
  float qm = q;
  qm = fmaxf(qm, __shfl_xor(qm, 8)); qm = fmaxf(qm, __shfl_xor(qm, 4));
  qm = fmaxf(qm, __shfl_xor(qm, 2)); qm = fmaxf(qm, __shfl_xor(qm, 1));
  float e = expf(q - qm);
  float es = e;
  es += __shfl_xor(es, 8); es += __shfl_xor(es, 4);
  es += __shfl_xor(es, 2); es += __shfl_xor(es, 1);
  if (lane < 16) att_lds[wave][lane] = e / es;
  __syncthreads();

  // deterministic serial bucket-accumulate (no atomics)
  if (lane == 0) {
#pragma unroll
    for (int n = 0; n < 16; ++n) {
      int lb = labels[(size_t)batch * 16 + n];
      acc[wave][lb - 1] += att_lds[wave][n];
    }
  }
  __syncthreads();

  float* ob = out + (size_t)batch * 75;
  ob[lane] = logf(acc[wave][lane]);
  if (lane < 11) ob[64 + lane] = logf(acc[wave][64 + lane]);
}

extern "C" void kernel_launch(void* const* d_in, const int* in_sizes, int n_in,
                              void* d_out, int out_size, void* d_ws, size_t ws_size,
                              hipStream_t stream) {
  const float* z      = (const float*)d_in[0];
  const int*   labels = (const int*)d_in[1];
  const float* Kp     = (const float*)d_in[2];
  const float* Lm     = (const float*)d_in[3];
  const float* Bm     = (const float*)d_in[4];
  const float* base   = (const float*)d_in[5];
  float* out = (float*)d_out;

  const int bsz = in_sizes[0] / ZFULL;  // 8192

  const size_t B_bytes = (size_t)256 * 5 * 2 * 64 * 8 * sizeof(ushort);  // 2.62 MB
  int CH = bsz;
  while (CH > 128) {
    size_t A_bytes = (size_t)(CH / 16) * 5 * 2 * 64 * 8 * sizeof(ushort);
    size_t need = B_bytes + A_bytes + (size_t)CH * 4096 * sizeof(float);
    if (need <= ws_size) break;
    CH >>= 1;
  }
  ushort* Bpk = (ushort*)d_ws;
  ushort* Apk = (ushort*)((char*)d_ws + B_bytes);
  size_t A_bytes = (size_t)(CH / 16) * 5 * 2 * 64 * 8 * sizeof(ushort);
  float* rates = (float*)((char*)d_ws + B_bytes + A_bytes);

  pack_B<<<(256 * 640 + 255) / 256, 256, 0, stream>>>(Kp, Lm, Bpk);

  for (int b0 = 0; b0 < bsz; b0 += CH) {
    int a_threads = (CH / 16) * 640;
    pack_A<<<(a_threads + 255) / 256, 256, 0, stream>>>(z, labels, Apk, b0, CH);
    dim3 g(CH / 128, 32);
    gemm_mfma<<<g, 256, 0, stream>>>(Apk, Bpk, base, rates);
    solve_kernel<<<CH / 4, 256, 0, stream>>>(rates, labels, Bm, out, b0);
  }
}